// Round 2
// baseline (362.819 us; speedup 1.0000x reference)
//
#include <hip/hip_runtime.h>

#define BINS 256
#define NCOPY 32                 // one histogram copy per lane-pair (lane & 31)
#define ROWS (BINS + 1)          // +1 dump row for out-of-range / NaN
constexpr int TPB  = 512;        // 8 waves/block
constexpr int GRID = 1024;       // 4 blocks/CU (LDS-limited), 32 waves/CU

typedef float f32x4 __attribute__((ext_vector_type(4)));

// lds layout: lds[bin * 32 + copy], copy = lane & 31.
// bank = (bin*32 + copy) & 31 = copy  ->  each lane always hits its own bank,
// independent of the (normal-distributed, heavily clustered) bin value.
// Residual: lanes i and i+32 share a copy -> 2-way same-address only when
// they also share a bin (2-way LDS conflict is ~free, m136).
__device__ __forceinline__ void bin_one(float v, unsigned* h) {
    // Reference: idx = floor((x - (-4)) * 32); idx = min(idx, 255);
    // valid iff -4 <= x <= 4 (NaN fails -> discard). Branchless: route
    // invalid lanes to dump row 256 so the ds_atomic is unconditional.
    // Arithmetic kept bit-identical to the verified kernel: add then mul
    // (no fma contraction of the bin edge), but floorf is dropped:
    //   t >= 0  -> trunc == floor;
    //   t <  0  -> v < -4 -> invalid -> dump row regardless;
    //   NaN/inf -> v_cvt saturates/zeros -> masked by valid check.
    float t = (v + 4.0f) * 32.0f;
    int b = (int)t;
    b = b > (BINS - 1) ? (BINS - 1) : b;
    bool valid = (v >= -4.0f) && (v <= 4.0f);
    int idx = valid ? b : BINS;
    atomicAdd(&h[idx << 5], 1u);
}

__global__ void zero_out(float* __restrict__ out) {
    int i = blockIdx.x * blockDim.x + threadIdx.x;
    if (i < 2 * BINS) out[i] = 0.0f;
}

__global__ __launch_bounds__(TPB) void hist_main(
        const f32x4* __restrict__ x4, int n4,
        const float* __restrict__ x, int n,
        float* __restrict__ out) {
    __shared__ unsigned lds[ROWS * NCOPY];   // 32.9 KB -> 4 blocks/CU
    const int tid = threadIdx.x;

    for (int i = tid; i < ROWS * NCOPY; i += TPB) lds[i] = 0;
    __syncthreads();

    unsigned* h = lds + (tid & 31);          // lane-pair-private copy

    const int stride = gridDim.x * TPB;
    int i = blockIdx.x * TPB + tid;

    // Regular (cached) dwordx4 loads: the harness rewrites the 256 MiB input
    // right before the timed iteration, so part of it is L3-resident —
    // nontemporal loads were bypassing that. 8 loads in flight per thread.
    for (; i + 7 * stride < n4; i += 8 * stride) {
        f32x4 v[8];
        #pragma unroll
        for (int j = 0; j < 8; ++j)
            v[j] = x4[i + j * stride];
        #pragma unroll
        for (int j = 0; j < 8; ++j) {
            bin_one(v[j].x, h); bin_one(v[j].y, h);
            bin_one(v[j].z, h); bin_one(v[j].w, h);
        }
    }
    for (; i < n4; i += stride) {
        f32x4 a = x4[i];
        bin_one(a.x, h); bin_one(a.y, h); bin_one(a.z, h); bin_one(a.w, h);
    }
    if (blockIdx.x == 0) {          // scalar tail (n % 4), none for n = 2^26
        int tail = n - n4 * 4;
        if (tid < tail) bin_one(x[n4 * 4 + tid], h);
    }

    __syncthreads();

    // Merge the 32 copies per bin. Rotation (c + tid) & 31 makes lane i read
    // bank (c + i) & 31 -> all 32 banks covered per read, 2-way max (free).
    // Counts are integers < 2^24 -> every f32 add is exact -> deterministic.
    if (tid < BINS) {
        unsigned total = 0;
        #pragma unroll
        for (int c = 0; c < NCOPY; ++c)
            total += lds[(tid << 5) + ((c + tid) & 31)];
        float f = (float)total;
        atomicAdd(&out[tid], f);
        atomicAdd(&out[BINS + tid], f);
    }
}

extern "C" void kernel_launch(void* const* d_in, const int* in_sizes, int n_in,
                              void* d_out, int out_size, void* d_ws, size_t ws_size,
                              hipStream_t stream) {
    const float* x = (const float*)d_in[0];
    const int n = in_sizes[0];
    const int n4 = n / 4;
    float* out = (float*)d_out;

    zero_out<<<1, 2 * BINS, 0, stream>>>(out);
    hist_main<<<GRID, TPB, 0, stream>>>((const f32x4*)x, n4, x, n, out);
}

// Round 3
// 339.277 us; speedup vs baseline: 1.0694x; 1.0694x over previous
//
#include <hip/hip_runtime.h>

#define BINS 256
#define NCOPY 32                 // one histogram copy per lane-pair (lane & 31)
#define ROWS (BINS + 1)          // +1 dump row for out-of-range
constexpr int TPB  = 512;        // 8 waves/block
constexpr int GRID = 1024;       // 4 blocks/CU (LDS-limited), 32 waves/CU

typedef float f32x4 __attribute__((ext_vector_type(4)));

// lds layout: lds[bin * 32 + copy], copy = lane & 31.
// bank = (bin*32 + copy) & 31 = copy  ->  each lane always hits its own bank,
// independent of the (normal-distributed, heavily clustered) bin value.
// Residual: lanes i and i+32 share a copy -> 2-way same-address only when
// they also share a bin (2-way LDS conflict is ~free, m136).
__device__ __forceinline__ void bin_one(float v, unsigned* h) {
    // Reference: idx = floor((x - (-4)) * 32); idx = min(idx, 255);
    // valid iff -4 <= x <= 4. Branchless: route invalid lanes to dump
    // row 256 so the ds_atomic is unconditional.
    // (v + 4.0f) * 32.0f kept as separate add+mul: matches the reference's
    // (x - LO) * scale rounding exactly (absmax must stay 0).
    // trunc instead of floor is safe: t < 0 only when v < -4 -> invalid ->
    // dump row regardless (verified round 2, absmax = 0).
    // fabsf(v) <= 4 is one v_cmp with the free abs() modifier, identical to
    // (v >= -4 && v <= 4); NaN fails either way.
    float t = (v + 4.0f) * 32.0f;
    int b = (int)t;
    b = b > (BINS - 1) ? (BINS - 1) : b;
    bool valid = fabsf(v) <= 4.0f;
    int idx = valid ? b : BINS;
    atomicAdd(&h[idx << 5], 1u);
}

__global__ void zero_out(float* __restrict__ out) {
    int i = blockIdx.x * blockDim.x + threadIdx.x;
    if (i < 2 * BINS) out[i] = 0.0f;
}

__global__ __launch_bounds__(TPB) void hist_main(
        const f32x4* __restrict__ x4, int n4,
        const float* __restrict__ x, int n,
        float* __restrict__ out) {
    __shared__ unsigned lds[ROWS * NCOPY];   // 32.9 KB -> 4 blocks/CU
    const int tid = threadIdx.x;

    for (int i = tid; i < ROWS * NCOPY; i += TPB) lds[i] = 0;
    __syncthreads();

    unsigned* h = lds + (tid & 31);          // lane-pair-private copy

    const int stride = gridDim.x * TPB;
    int i = blockIdx.x * TPB + tid;

    // Nontemporal streaming loads: the harness's two ~1 GiB restore fills
    // sweep L3 every iteration, so x is never cache-resident at kernel
    // start — cached loads measured +23 us (R2). 8 dwordx4 in flight.
    for (; i + 7 * stride < n4; i += 8 * stride) {
        f32x4 v[8];
        #pragma unroll
        for (int j = 0; j < 8; ++j)
            v[j] = __builtin_nontemporal_load(&x4[i + j * stride]);
        #pragma unroll
        for (int j = 0; j < 8; ++j) {
            bin_one(v[j].x, h); bin_one(v[j].y, h);
            bin_one(v[j].z, h); bin_one(v[j].w, h);
        }
    }
    for (; i < n4; i += stride) {
        f32x4 a = __builtin_nontemporal_load(&x4[i]);
        bin_one(a.x, h); bin_one(a.y, h); bin_one(a.z, h); bin_one(a.w, h);
    }
    if (blockIdx.x == 0) {          // scalar tail (n % 4), none for n = 2^26
        int tail = n - n4 * 4;
        if (tid < tail) bin_one(x[n4 * 4 + tid], h);
    }

    __syncthreads();

    // Merge the 32 copies per bin. Rotation (c + tid) & 31 makes lane i read
    // bank (c + i) & 31 -> all 32 banks covered per read, 2-way max (free).
    // Counts are integers < 2^24 -> every f32 add is exact -> deterministic.
    if (tid < BINS) {
        unsigned total = 0;
        #pragma unroll
        for (int c = 0; c < NCOPY; ++c)
            total += lds[(tid << 5) + ((c + tid) & 31)];
        float f = (float)total;
        atomicAdd(&out[tid], f);
        atomicAdd(&out[BINS + tid], f);
    }
}

extern "C" void kernel_launch(void* const* d_in, const int* in_sizes, int n_in,
                              void* d_out, int out_size, void* d_ws, size_t ws_size,
                              hipStream_t stream) {
    const float* x = (const float*)d_in[0];
    const int n = in_sizes[0];
    const int n4 = n / 4;
    float* out = (float*)d_out;

    zero_out<<<1, 2 * BINS, 0, stream>>>(out);
    hist_main<<<GRID, TPB, 0, stream>>>((const f32x4*)x, n4, x, n, out);
}